// Round 12
// baseline (469.871 us; speedup 1.0000x reference)
//
#include <hip/hip_runtime.h>
#include <hip/hip_bf16.h>

typedef unsigned short u16;
typedef __attribute__((ext_vector_type(8))) short bf16x8;
typedef __attribute__((ext_vector_type(4))) float f32x4;
typedef __attribute__((ext_vector_type(8))) unsigned short ushort8;

#define FEAT 1024
#define NOUT 16384
#define EPS 1e-6f
#define NW 16            // K windows of 64

#define GLOBAL_AS __attribute__((address_space(1)))
#define LDS_AS __attribute__((address_space(3)))

__device__ __forceinline__ void load16_to_lds(const u16* g, u16* l) {
    __builtin_amdgcn_global_load_lds((const GLOBAL_AS void*)g, (LDS_AS void*)l, 16, 0, 0);
}

__device__ __forceinline__ u16 f32_to_bf16_bits(float f) {
    __hip_bfloat16 h = __float2bfloat16(f);
    return *reinterpret_cast<u16*>(&h);
}

__device__ __forceinline__ float bf16_bits_to_f32(u16 b) {
    unsigned u = ((unsigned)b) << 16;
    float f;
    __builtin_memcpy(&f, &u, 4);
    return f;
}

// Fused prep: blocks [0, 8192) build Wb (epilogue permutation baked in:
// Wb row p holds logical W row (p&~63)|((p&15)<<2)|((p>>4)&3)); blocks
// [8192, 12288) cast x -> bf16.
__global__ void prep_kernel(const float* __restrict__ w, u16* __restrict__ Wb,
                            const float* __restrict__ x, u16* __restrict__ Xb) {
    const int bid = blockIdx.x;
    if (bid < 8192) {
        const int t  = bid * 256 + threadIdx.x;
        const int p  = t >> 7;
        const int k0 = (t & 127) << 3;
        const int o  = (p & ~63) | ((p & 15) << 2) | ((p >> 4) & 3);
        const int ai = o >> 9;
        const int bi = (o >> 4) & 31;
        const int ci = o & 15;
        const float* A = w + ai * FEAT + k0;
        const float* B = w + (32 + bi) * FEAT + k0;
        const float* C = w + (64 + ci) * FEAT + k0;
        ushort8 r;
#pragma unroll
        for (int j = 0; j < 8; ++j) r[j] = f32_to_bf16_bits(A[j] * B[j] * C[j]);
        *reinterpret_cast<ushort8*>(Wb + (size_t)t * 8) = r;
    } else {
        const int t = (bid - 8192) * 256 + threadIdx.x;
        const float4* xv = reinterpret_cast<const float4*>(x) + (size_t)t * 2;
        const float4 f0 = xv[0];
        const float4 f1 = xv[1];
        float vals[8] = {f0.x, f0.y, f0.z, f0.w, f1.x, f1.y, f1.z, f1.w};
        ushort8 r;
#pragma unroll
        for (int j = 0; j < 8; ++j) r[j] = f32_to_bf16_bits(vals[j]);
        *reinterpret_cast<ushort8*>(Xb + (size_t)t * 8) = r;
    }
}

// ---- 128x256 GEMM, 3-buffer publish-ahead, 1 barrier/window, staggered ----
// 512 threads = 8 waves (2 M-halves x 4 N-quarters), wave tile 64x64
// (acc[4][4] f32x4 = 64 regs). LDS: 3 windows x 48 KiB = 144 KiB; window =
// A[128][64] + B[256][64] bf16, 128B rows, 8x16B chunks XOR-swizzled
// (slot = chunk ^ (row&7)) -> quarter-wave conflict-free ds_read_b128.
// Window t (buf = t%3): BOTH k-halves published at its opening barrier
// (staged during t-2, vmcnt'd at end of t-1). So waves process halves in
// OPPOSITE orders (even waves k0->k1, odd k1->k0): half the waves feed the
// LDS pipe while the other half feed the MFMA pipe (m114 overlap).
// Per window: stage A(t+2) | half1 | stage B(t+2) | half2 | vmcnt(6) | bar.
// Ledger: outstanding at end of t = t's 6 + (t+... = 12; vmcnt(6) retires
// exactly window (t+1)'s 6 loads -> published by the barrier. WAR: stage
// target (t+2)%3 == (t-1)%3, whose reads retired before the end-of-(t-1)
// barrier (MFMA operand dependency). Tail: t==NW-2 -> vmcnt(0); t==NW-1 ->
// no wait/barrier.

#define WSZ 24576   // u16 per window (48 KiB)

#define STAGE_A(tt, nb) do {                                                  \
    const u16* g = gAs + (size_t)(tt) * 64;                                   \
    load16_to_lds(g,             (nb) + wv * 512);                            \
    load16_to_lds(g + 64 * FEAT, (nb) + 4096 + wv * 512);                     \
} while (0)

#define STAGE_B(tt, nb) do {                                                  \
    const u16* g = gBs + (size_t)(tt) * 64;                                   \
    load16_to_lds(g,               (nb) + 8192  + wv * 512);                  \
    load16_to_lds(g + 64  * FEAT,  (nb) + 12288 + wv * 512);                  \
    load16_to_lds(g + 128 * FEAT,  (nb) + 16384 + wv * 512);                  \
    load16_to_lds(g + 192 * FEAT,  (nb) + 20480 + wv * 512);                  \
} while (0)

#define RD_A(dst, mi, kh, wb) dst = *reinterpret_cast<const bf16x8*>(         \
    (wb) + (wm * 64 + (mi) * 16 + fr) * 64 + (((((kh) << 2) | kg)) ^ (fr & 7)) * 8)
#define RD_B(dst, nj, kh, wb) dst = *reinterpret_cast<const bf16x8*>(         \
    (wb) + 8192 + (wn * 64 + (nj) * 16 + fr) * 64 + (((((kh) << 2) | kg)) ^ (fr & 7)) * 8)

#define BAR() do {                                                            \
    __builtin_amdgcn_sched_barrier(0);                                        \
    __builtin_amdgcn_s_barrier();                                             \
    __builtin_amdgcn_sched_barrier(0);                                        \
} while (0)

#define HALFC(kh, wb) do {                                                    \
    bf16x8 a0, a1, a2, a3, b0, b1, b2, b3;                                    \
    RD_A(a0, 0, kh, wb); RD_A(a1, 1, kh, wb);                                 \
    RD_A(a2, 2, kh, wb); RD_A(a3, 3, kh, wb);                                 \
    RD_B(b0, 0, kh, wb); RD_B(b1, 1, kh, wb);                                 \
    RD_B(b2, 2, kh, wb); RD_B(b3, 3, kh, wb);                                 \
    __builtin_amdgcn_s_setprio(1);                                            \
    acc[0][0] = __builtin_amdgcn_mfma_f32_16x16x32_bf16(a0, b0, acc[0][0], 0, 0, 0); \
    acc[0][1] = __builtin_amdgcn_mfma_f32_16x16x32_bf16(a0, b1, acc[0][1], 0, 0, 0); \
    acc[0][2] = __builtin_amdgcn_mfma_f32_16x16x32_bf16(a0, b2, acc[0][2], 0, 0, 0); \
    acc[0][3] = __builtin_amdgcn_mfma_f32_16x16x32_bf16(a0, b3, acc[0][3], 0, 0, 0); \
    acc[1][0] = __builtin_amdgcn_mfma_f32_16x16x32_bf16(a1, b0, acc[1][0], 0, 0, 0); \
    acc[1][1] = __builtin_amdgcn_mfma_f32_16x16x32_bf16(a1, b1, acc[1][1], 0, 0, 0); \
    acc[1][2] = __builtin_amdgcn_mfma_f32_16x16x32_bf16(a1, b2, acc[1][2], 0, 0, 0); \
    acc[1][3] = __builtin_amdgcn_mfma_f32_16x16x32_bf16(a1, b3, acc[1][3], 0, 0, 0); \
    acc[2][0] = __builtin_amdgcn_mfma_f32_16x16x32_bf16(a2, b0, acc[2][0], 0, 0, 0); \
    acc[2][1] = __builtin_amdgcn_mfma_f32_16x16x32_bf16(a2, b1, acc[2][1], 0, 0, 0); \
    acc[2][2] = __builtin_amdgcn_mfma_f32_16x16x32_bf16(a2, b2, acc[2][2], 0, 0, 0); \
    acc[2][3] = __builtin_amdgcn_mfma_f32_16x16x32_bf16(a2, b3, acc[2][3], 0, 0, 0); \
    acc[3][0] = __builtin_amdgcn_mfma_f32_16x16x32_bf16(a3, b0, acc[3][0], 0, 0, 0); \
    acc[3][1] = __builtin_amdgcn_mfma_f32_16x16x32_bf16(a3, b1, acc[3][1], 0, 0, 0); \
    acc[3][2] = __builtin_amdgcn_mfma_f32_16x16x32_bf16(a3, b2, acc[3][2], 0, 0, 0); \
    acc[3][3] = __builtin_amdgcn_mfma_f32_16x16x32_bf16(a3, b3, acc[3][3], 0, 0, 0); \
    __builtin_amdgcn_s_setprio(0);                                            \
} while (0)

__global__ __launch_bounds__(512, 2) void gemm_kernel(const u16* __restrict__ Xb,
                                                      const u16* __restrict__ Wb,
                                                      u16* __restrict__ Y) {
    __shared__ u16 lds[3 * WSZ];   // 144 KiB

    const int tid  = threadIdx.x;
    const int lane = tid & 63;
    const int wv   = tid >> 6;     // wave 0..7
    const int wm   = wv >> 2;      // M-half (0..1)
    const int wn   = wv & 3;       // N-quarter (0..3)
    const int fr   = lane & 15;
    const int kg   = lane >> 4;
    const int stag = (wv ^ (wv >> 2)) & 1;   // one of each order per SIMD

    // XCD-aware mapping: xcd owns col-blocks [xcd*8, xcd*8+8) (B panel 4MB,
    // L2-resident), walks rows with 4-col inner chunks.
    const int bid = blockIdx.x;            // 0..4095
    const int xcd = bid & 7;
    const int o   = bid >> 3;              // 0..511
    const int cb  = xcd * 8 + (o >> 8) * 4 + (o & 3);  // 0..63
    const int rb  = (o >> 2) & 63;                     // 0..63
    const int brow = rb * 128;
    const int bcol = cb * 256;

    // staging sources (pre-swizzled global, linear LDS dest)
    const int srow = tid >> 3;                        // 0..63
    const int swz  = (lane & 7) ^ (lane >> 3);        // phys->logical chunk
    const u16* gAs = Xb + (size_t)(brow + srow) * FEAT + swz * 8;
    const u16* gBs = Wb + (size_t)(bcol + srow) * FEAT + swz * 8;

    f32x4 acc[4][4] = {};

    // prologue: stage windows 0 and 1 (12 loads); vmcnt(6) -> window 0 done.
    STAGE_A(0, lds);
    STAGE_B(0, lds);
    STAGE_A(1, lds + WSZ);
    STAGE_B(1, lds + WSZ);
    asm volatile("s_waitcnt vmcnt(6)" ::: "memory");
    BAR();

    int cur = 0;
    for (int t = 0; t < NW; ++t) {
        u16* wb = lds + cur * WSZ;
        const int nxti = (cur + 2 >= 3) ? (cur - 1) : (cur + 2);   // (cur+2)%3
        u16* nb = lds + nxti * WSZ;
        const bool st = (t < NW - 2);
        if (st) STAGE_A(t + 2, nb);
        if (stag) { HALFC(1, wb); } else { HALFC(0, wb); }
        if (st) STAGE_B(t + 2, nb);
        if (stag) { HALFC(0, wb); } else { HALFC(1, wb); }
        if (t < NW - 2) {
            asm volatile("s_waitcnt vmcnt(6)" ::: "memory");
            BAR();
        } else if (t == NW - 2) {
            asm volatile("s_waitcnt vmcnt(0)" ::: "memory");
            BAR();
        }
        cur = (cur + 1 == 3) ? 0 : (cur + 1);
    }

    // ------------- epilogue: packed coalesced bf16 stores -------------
    // fragment (nj, fr) = output col bcol + wn*64 + fr*4 + nj (perm in prep)
    const int colbase = bcol + wn * 64 + fr * 4;
#pragma unroll
    for (int mi = 0; mi < 4; ++mi) {
#pragma unroll
        for (int r = 0; r < 4; ++r) {
            const int row = brow + wm * 64 + mi * 16 + kg * 4 + r;
            const unsigned lo = (unsigned)f32_to_bf16_bits(acc[mi][0][r]) |
                                ((unsigned)f32_to_bf16_bits(acc[mi][1][r]) << 16);
            const unsigned hi = (unsigned)f32_to_bf16_bits(acc[mi][2][r]) |
                                ((unsigned)f32_to_bf16_bits(acc[mi][3][r]) << 16);
            uint2 pk; pk.x = lo; pk.y = hi;
            *reinterpret_cast<uint2*>(Y + (size_t)row * 32768 + colbase) = pk;
        }
    }
}

// Per-row scale: read bf16 y row, compute sum-of-squares from it, write fp32
// normalized row in-place over the same 64KB row slot.
__global__ __launch_bounds__(1024) void scale_kernel(const u16* __restrict__ Y,
                                                     float* __restrict__ out) {
    const int row = blockIdx.x;
    const int tid = threadIdx.x;
    const ushort8* yr = reinterpret_cast<const ushort8*>(Y + (size_t)row * 32768);
    const ushort8 v0 = yr[2 * tid];
    const ushort8 v1 = yr[2 * tid + 1];

    float f[16];
#pragma unroll
    for (int j = 0; j < 8; ++j) {
        f[j]     = bf16_bits_to_f32(v0[j]);
        f[8 + j] = bf16_bits_to_f32(v1[j]);
    }
    float ss = 0.f;
#pragma unroll
    for (int j = 0; j < 16; ++j) ss += f[j] * f[j];

#pragma unroll
    for (int off = 1; off < 64; off <<= 1) ss += __shfl_xor(ss, off, 64);
    __shared__ float wss[16];
    if ((tid & 63) == 0) wss[tid >> 6] = ss;
    __syncthreads();
    float tot = 0.f;
#pragma unroll
    for (int i = 0; i < 16; ++i) tot += wss[i];
    const float sc = rsqrtf(tot * (1.0f / (float)NOUT) + EPS);

    float4* orow = reinterpret_cast<float4*>(out + (size_t)row * NOUT) + tid * 4;
#pragma unroll
    for (int q = 0; q < 4; ++q) {
        float4 ov;
        ov.x = f[q * 4 + 0] * sc;
        ov.y = f[q * 4 + 1] * sc;
        ov.z = f[q * 4 + 2] * sc;
        ov.w = f[q * 4 + 3] * sc;
        orow[q] = ov;
    }
}

extern "C" void kernel_launch(void* const* d_in, const int* in_sizes, int n_in,
                              void* d_out, int out_size, void* d_ws, size_t ws_size,
                              hipStream_t stream) {
    const float* x = (const float*)d_in[0];   // (8192,1024) fp32
    const float* w = (const float*)d_in[1];   // (80,1024) fp32
    float* out = (float*)d_out;               // (8192,16384) fp32

    u16* Wb = (u16*)d_ws;                                      // 32 MiB
    u16* Xb = (u16*)((char*)d_ws + (size_t)NOUT * FEAT * 2);   // 16 MiB

    u16* Y = (u16*)d_out;   // bf16 y in first 32KB of each 64KB out row

    prep_kernel<<<12288, 256, 0, stream>>>(w, Wb, x, Xb);

    const int nblk = 4096;   // (8192/128) * (16384/256)
    gemm_kernel<<<nblk, 512, 0, stream>>>(Xb, Wb, Y);

    scale_kernel<<<8192, 1024, 0, stream>>>(Y, out);
}

// Round 13
// 451.682 us; speedup vs baseline: 1.0403x; 1.0403x over previous
//
#include <hip/hip_runtime.h>
#include <hip/hip_bf16.h>

typedef unsigned short u16;
typedef __attribute__((ext_vector_type(8))) short bf16x8;
typedef __attribute__((ext_vector_type(4))) float f32x4;
typedef __attribute__((ext_vector_type(8))) unsigned short ushort8;

#define FEAT 1024
#define NOUT 16384
#define EPS 1e-6f
#define NT 16            // K-tiles of 64

#define GLOBAL_AS __attribute__((address_space(1)))
#define LDS_AS __attribute__((address_space(3)))

__device__ __forceinline__ void load16_to_lds(const u16* g, u16* l) {
    __builtin_amdgcn_global_load_lds((const GLOBAL_AS void*)g, (LDS_AS void*)l, 16, 0, 0);
}

__device__ __forceinline__ u16 f32_to_bf16_bits(float f) {
    __hip_bfloat16 h = __float2bfloat16(f);
    return *reinterpret_cast<u16*>(&h);
}

__device__ __forceinline__ float bf16_bits_to_f32(u16 b) {
    unsigned u = ((unsigned)b) << 16;
    float f;
    __builtin_memcpy(&f, &u, 4);
    return f;
}

// Build Wb with a baked-in within-64-row permutation:
//   Wb[p] = W_row[ (p & ~63) | ((p&15)<<2) | ((p>>4)&3) ]
// so the 16x16-MFMA epilogue fragment (nj, fr) maps to 4 CONTIGUOUS output
// columns fr*4+nj (coalesced 8B packed stores).
__global__ void wbuild_kernel(const float* __restrict__ w, u16* __restrict__ Wb) {
    const int t  = blockIdx.x * 256 + threadIdx.x;
    const int p  = t >> 7;                      // Wb row (permuted position)
    const int k0 = (t & 127) << 3;
    const int o  = (p & ~63) | ((p & 15) << 2) | ((p >> 4) & 3);  // logical W row
    const int ai = o >> 9;
    const int bi = (o >> 4) & 31;
    const int ci = o & 15;
    const float* A = w + ai * FEAT + k0;
    const float* B = w + (32 + bi) * FEAT + k0;
    const float* C = w + (64 + ci) * FEAT + k0;
    ushort8 r;
#pragma unroll
    for (int j = 0; j < 8; ++j) r[j] = f32_to_bf16_bits(A[j] * B[j] * C[j]);
    *reinterpret_cast<ushort8*>(Wb + (size_t)t * 8) = r;
}

__global__ void xcast_kernel(const float* __restrict__ x, u16* __restrict__ Xb) {
    const int t = blockIdx.x * 256 + threadIdx.x;
    const float4* xv = reinterpret_cast<const float4*>(x) + (size_t)t * 2;
    const float4 f0 = xv[0];
    const float4 f1 = xv[1];
    float vals[8] = {f0.x, f0.y, f0.z, f0.w, f1.x, f1.y, f1.z, f1.w};
    ushort8 r;
#pragma unroll
    for (int j = 0; j < 8; ++j) r[j] = f32_to_bf16_bits(vals[j]);
    *reinterpret_cast<ushort8*>(Xb + (size_t)t * 8) = r;
}

// ---------------- 256x256 pipelined GEMM, 2 barriers/K-tile ----------------
// (verified best: r5 = 451.6us total, GEMM ~290us, 950 TF.)
// 512 threads = 8 waves (2 M-halves x 4 N-quarters), wave tile 128x64.
// LDS: 2 buffers x (A 256x64 + B 256x64) bf16 = 128 KiB,
// [buf][op][khalf][256 rows][32 cols], 16B chunks XOR-swizzled via global src.
// Per tile t (lives in buf = t&1), two halves:
//  half k0: reads k0 frags + MFMA; stages (t+1).Ak1, (t+1).Bk1 -> nbuf;
//           vmcnt(8) publishes THIS tile's k1; barrier.
//  half k1: reads k1 frags + MFMA; stages (t+2).Ak0, (t+2).Bk0 -> buf
//           (k0 regions dead: consumed before previous barrier);
//           vmcnt(8) publishes NEXT tile's k0; barrier.
// No lgkmcnt(0)/mid-barrier: ds_read->MFMA ordering is data-dependence
// (compiler emits counted lgkmcnt; LDS pipe drains under MFMA).

#define LDSOFF(buf, isB, kh) (((buf) << 15) + ((isB) << 14) + ((kh) << 13))

#define STAGE(isB, tt, kh, buf) do {                                          \
    const u16* g = ((isB) ? gB : gA) + (size_t)(tt) * 64 + (kh) * 32 + w * 32768; \
    u16* l = lds + LDSOFF(buf, isB, kh) + w * 1024;                           \
    load16_to_lds(g, l);                                                      \
    load16_to_lds(g + 16384, l + 512);                                        \
} while (0)

#define RD_A(dst, mi, ks, buf) dst = *reinterpret_cast<const bf16x8*>(        \
    lds + LDSOFF(buf, 0, ks) + (wm * 128 + (mi) * 16 + fr) * 32 + ((kg ^ ((fr >> 1) & 3)) << 3))
#define RD_B(dst, nj, ks, buf) dst = *reinterpret_cast<const bf16x8*>(        \
    lds + LDSOFF(buf, 1, ks) + (wn * 64 + (nj) * 16 + fr) * 32 + ((kg ^ ((fr >> 1) & 3)) << 3))

#define BAR() do {                                                            \
    __builtin_amdgcn_sched_barrier(0);                                        \
    __builtin_amdgcn_s_barrier();                                             \
    __builtin_amdgcn_sched_barrier(0);                                        \
} while (0)

#define MFMAQ(mibase) do {                                                    \
    __builtin_amdgcn_s_setprio(1);                                            \
    _Pragma("unroll")                                                         \
    for (int mi = 0; mi < 4; ++mi) {                                          \
        acc[(mibase)+mi][0] = __builtin_amdgcn_mfma_f32_16x16x32_bf16(a[mi], b[0], acc[(mibase)+mi][0], 0, 0, 0); \
        acc[(mibase)+mi][1] = __builtin_amdgcn_mfma_f32_16x16x32_bf16(a[mi], b[1], acc[(mibase)+mi][1], 0, 0, 0); \
        acc[(mibase)+mi][2] = __builtin_amdgcn_mfma_f32_16x16x32_bf16(a[mi], b[2], acc[(mibase)+mi][2], 0, 0, 0); \
        acc[(mibase)+mi][3] = __builtin_amdgcn_mfma_f32_16x16x32_bf16(a[mi], b[3], acc[(mibase)+mi][3], 0, 0, 0); \
    }                                                                         \
    __builtin_amdgcn_s_setprio(0);                                            \
} while (0)

// half-end counted waits (loads are 2 per STAGE; 8 = 4 stages in flight)
#define WAIT_H1(t) do {                                                       \
    if ((t) == NT - 1) { asm volatile("s_waitcnt vmcnt(0)" ::: "memory"); }   \
    else               { asm volatile("s_waitcnt vmcnt(8)" ::: "memory"); }   \
} while (0)
#define WAIT_H2(t) do {                                                       \
    if ((t) < NT - 2)       { asm volatile("s_waitcnt vmcnt(8)" ::: "memory"); } \
    else if ((t) == NT - 2) { asm volatile("s_waitcnt vmcnt(4)" ::: "memory"); } \
} while (0)

#define HALF(kh, buf, doStage, stT, stKh, stBuf, WAITC) do {                  \
    RD_A(a[0], 0, kh, buf); RD_A(a[1], 1, kh, buf);                           \
    RD_A(a[2], 2, kh, buf); RD_A(a[3], 3, kh, buf);                           \
    RD_B(b[0], 0, kh, buf); RD_B(b[1], 1, kh, buf);                           \
    RD_B(b[2], 2, kh, buf); RD_B(b[3], 3, kh, buf);                           \
    if (doStage) STAGE(0, stT, stKh, stBuf);                                  \
    MFMAQ(0);                                                                 \
    RD_A(a[0], 4, kh, buf); RD_A(a[1], 5, kh, buf);                           \
    RD_A(a[2], 6, kh, buf); RD_A(a[3], 7, kh, buf);                           \
    if (doStage) STAGE(1, stT, stKh, stBuf);                                  \
    MFMAQ(4);                                                                 \
    WAITC;                                                                    \
    BAR();                                                                    \
} while (0)

#define TILE_BODY(t, buf, nbuf) do {                                          \
    HALF(0, buf, (t) < NT - 1, (t) + 1, 1, nbuf, WAIT_H1(t));                 \
    HALF(1, buf, (t) < NT - 2, (t) + 2, 0, buf,  WAIT_H2(t));                 \
} while (0)

__global__ __launch_bounds__(512, 2) void gemm_kernel(const u16* __restrict__ Xb,
                                                      const u16* __restrict__ Wb,
                                                      u16* __restrict__ Y) {
    __shared__ u16 lds[65536];   // 128 KiB

    const int tid  = threadIdx.x;
    const int lane = tid & 63;
    const int w    = tid >> 6;     // wave 0..7
    const int wm   = w >> 2;       // M-half
    const int wn   = w & 3;        // N-quarter
    const int fr   = lane & 15;
    const int kg   = lane >> 4;

    // XCD-aware 2D mapping: xcd = bid%8 owns col-blocks [xcd*8, xcd*8+8),
    // walks rows with 4-col inner chunks (W panel L2-resident).
    const int bid = blockIdx.x;            // 0..2047
    const int xcd = bid & 7;
    const int o   = bid >> 3;              // 0..255
    const int cb  = xcd * 8 + (o >> 7) * 4 + (o & 3);  // 0..63
    const int rb  = (o >> 2) & 31;                     // 0..31
    const int brow = rb * 256;
    const int bcol = cb * 256;

    // per-thread staging source (pre-swizzled global, linear LDS dest)
    const int srow   = lane >> 2;                       // 0..15
    const int kchunk = (lane & 3) ^ ((lane >> 3) & 3);  // phys->logical swizzle
    const u16* gA = Xb + (size_t)(brow + srow) * FEAT + kchunk * 8;
    const u16* gB = Wb + (size_t)(bcol + srow) * FEAT + kchunk * 8;

    f32x4 acc[8][4] = {};
    bf16x8 a[4], b[4];

    // prologue: tile 0 fully (buf0) + tile1 k0 halves (buf1) = 12 loads;
    // vmcnt(8) -> oldest 4 (t0.Ak0 + t0.Bk0) landed before first reads.
    STAGE(0, 0, 0, 0);
    STAGE(1, 0, 0, 0);
    STAGE(0, 0, 1, 0);
    STAGE(1, 0, 1, 0);
    STAGE(0, 1, 0, 1);
    STAGE(1, 1, 0, 1);
    asm volatile("s_waitcnt vmcnt(8)" ::: "memory");
    BAR();

    for (int tt = 0; tt < NT; tt += 2) {
        TILE_BODY(tt, 0, 1);
        TILE_BODY(tt + 1, 1, 0);
    }

    // ------------- epilogue: packed coalesced bf16 stores -------------
    // fragment (nj, fr) = output col bcol + wn*64 + fr*4 + nj (perm in wbuild)
    const int colbase = bcol + wn * 64 + fr * 4;
#pragma unroll
    for (int mi = 0; mi < 8; ++mi) {
#pragma unroll
        for (int r = 0; r < 4; ++r) {
            const int row = brow + wm * 128 + mi * 16 + kg * 4 + r;
            const unsigned lo = (unsigned)f32_to_bf16_bits(acc[mi][0][r]) |
                                ((unsigned)f32_to_bf16_bits(acc[mi][1][r]) << 16);
            const unsigned hi = (unsigned)f32_to_bf16_bits(acc[mi][2][r]) |
                                ((unsigned)f32_to_bf16_bits(acc[mi][3][r]) << 16);
            uint2 pk; pk.x = lo; pk.y = hi;
            *reinterpret_cast<uint2*>(Y + (size_t)row * 32768 + colbase) = pk;
        }
    }
}

// Per-row scale: read bf16 y row, compute sum-of-squares from it (bf16-
// quantized ss: rel err <=0.4%, far under threshold), write fp32 normalized
// row in-place over the same 64KB row slot (reads consumed before writes).
__global__ __launch_bounds__(1024) void scale_kernel(const u16* __restrict__ Y,
                                                     float* __restrict__ out) {
    const int row = blockIdx.x;
    const int tid = threadIdx.x;
    const ushort8* yr = reinterpret_cast<const ushort8*>(Y + (size_t)row * 32768);
    const ushort8 v0 = yr[2 * tid];
    const ushort8 v1 = yr[2 * tid + 1];

    float f[16];
#pragma unroll
    for (int j = 0; j < 8; ++j) {
        f[j]     = bf16_bits_to_f32(v0[j]);
        f[8 + j] = bf16_bits_to_f32(v1[j]);
    }
    float ss = 0.f;
#pragma unroll
    for (int j = 0; j < 16; ++j) ss += f[j] * f[j];

#pragma unroll
    for (int off = 1; off < 64; off <<= 1) ss += __shfl_xor(ss, off, 64);
    __shared__ float wss[16];
    if ((tid & 63) == 0) wss[tid >> 6] = ss;
    __syncthreads();
    float tot = 0.f;
#pragma unroll
    for (int i = 0; i < 16; ++i) tot += wss[i];
    const float sc = rsqrtf(tot * (1.0f / (float)NOUT) + EPS);

    float4* orow = reinterpret_cast<float4*>(out + (size_t)row * NOUT) + tid * 4;
#pragma unroll
    for (int q = 0; q < 4; ++q) {
        float4 ov;
        ov.x = f[q * 4 + 0] * sc;
        ov.y = f[q * 4 + 1] * sc;
        ov.z = f[q * 4 + 2] * sc;
        ov.w = f[q * 4 + 3] * sc;
        orow[q] = ov;
    }
}

extern "C" void kernel_launch(void* const* d_in, const int* in_sizes, int n_in,
                              void* d_out, int out_size, void* d_ws, size_t ws_size,
                              hipStream_t stream) {
    const float* x = (const float*)d_in[0];   // (8192,1024) fp32
    const float* w = (const float*)d_in[1];   // (80,1024) fp32
    float* out = (float*)d_out;               // (8192,16384) fp32

    const int M = in_sizes[0] / FEAT;         // 8192

    u16* Wb = (u16*)d_ws;                                      // 32 MiB
    u16* Xb = (u16*)((char*)d_ws + (size_t)NOUT * FEAT * 2);   // 16 MiB

    u16* Y = (u16*)d_out;   // bf16 y in first 32KB of each 64KB out row

    wbuild_kernel<<<(NOUT * (FEAT / 8)) / 256, 256, 0, stream>>>(w, Wb);
    xcast_kernel<<<(M * FEAT / 8) / 256, 256, 0, stream>>>(x, Xb);

    const int nblk = (M / 256) * (NOUT / 256);   // 2048
    gemm_kernel<<<nblk, 512, 0, stream>>>(Xb, Wb, Y);

    scale_kernel<<<M, 1024, 0, stream>>>(Y, out);
}